// Round 1
// baseline (570.040 us; speedup 1.0000x reference)
//
#include <hip/hip_runtime.h>
#include <math.h>

#define T_TOK 4096
#define D_DIM 1024
#define E_EXP 8
#define F_DIM 4096
#define BM 128
#define BN 128
#define BK 32
#define LDK 40          // padded LDS row stride (bf16 elems): 20 dwords -> conflict-light b128
#define MAX_TILES 40    // sum_e ceil(cnt_e/128) <= 4096/128 + 7 = 39
#define KSPLIT 4        // gemm2 split-K factor (occupancy fix)

typedef __attribute__((ext_vector_type(8))) short short8;
typedef __attribute__((ext_vector_type(4))) float float4v;

__device__ __forceinline__ short f2b(float f) {
    union { float f; unsigned u; } v; v.f = f;
    unsigned r = v.u + 0x7fffu + ((v.u >> 16) & 1u);   // RNE to bf16
    return (short)(r >> 16);
}

// ---------------- router: fp32 logits + argmax (exact routing) ----------------
__global__ void router_kernel(const float* __restrict__ x, const float* __restrict__ gw,
                              int* __restrict__ eid, int* __restrict__ rnk,
                              int* __restrict__ counts) {
    int lane = threadIdx.x & 63;
    int wave = threadIdx.x >> 6;
    int t = blockIdx.x * 4 + wave;
    const float* xr = x + (size_t)t * D_DIM;
    float p[E_EXP];
#pragma unroll
    for (int e = 0; e < E_EXP; ++e) p[e] = 0.f;
#pragma unroll
    for (int i = 0; i < D_DIM / 64; ++i) {
        float v = xr[lane + 64 * i];
#pragma unroll
        for (int e = 0; e < E_EXP; ++e)
            p[e] = fmaf(v, gw[e * D_DIM + lane + 64 * i], p[e]);
    }
#pragma unroll
    for (int off = 32; off > 0; off >>= 1) {
#pragma unroll
        for (int e = 0; e < E_EXP; ++e) p[e] += __shfl_down(p[e], off, 64);
    }
    if (lane == 0) {
        int best = 0; float bv = p[0];
#pragma unroll
        for (int e = 1; e < E_EXP; ++e) if (p[e] > bv) { bv = p[e]; best = e; }
        eid[t] = best;
        rnk[t] = atomicAdd(&counts[best], 1);
    }
}

// ---------------- prefix + tile map (trivial, E=8) ----------------
__global__ void prefix_kernel(const int* __restrict__ counts, int* __restrict__ offsets,
                              int* __restrict__ tmap) {
    int off = 0;
    offsets[0] = 0;
    int nt = 0;
    for (int e = 0; e < E_EXP; ++e) {
        int c = counts[e];
        for (int m0 = 0; m0 < c; m0 += BM) {
            tmap[nt * 3 + 0] = e;
            tmap[nt * 3 + 1] = off + m0;
            tmap[nt * 3 + 2] = (c - m0 < BM) ? (c - m0) : BM;
            ++nt;
        }
        off += c;
        offsets[e + 1] = off;
    }
    for (; nt < MAX_TILES; ++nt) tmap[nt * 3 + 2] = 0;
}

__global__ void scatter_kernel(const int* __restrict__ eid, const int* __restrict__ rnk,
                               const int* __restrict__ offsets, int* __restrict__ sorted) {
    int t = blockIdx.x * 256 + threadIdx.x;
    sorted[offsets[eid[t]] + rnk[t]] = t;
}

// ---------------- x: fp32 -> bf16, same layout ----------------
__global__ __launch_bounds__(256) void cvt_x_kernel(const float* __restrict__ x,
                                                    short* __restrict__ xb) {
    size_t base = ((size_t)blockIdx.x * 256 + threadIdx.x) * 16;
    float4v f0 = *(const float4v*)(x + base);
    float4v f1 = *(const float4v*)(x + base + 4);
    float4v f2 = *(const float4v*)(x + base + 8);
    float4v f3 = *(const float4v*)(x + base + 12);
    short8 s0, s1;
#pragma unroll
    for (int c = 0; c < 4; ++c) {
        s0[c] = f2b(f0[c]); s0[4 + c] = f2b(f1[c]);
        s1[c] = f2b(f2[c]); s1[4 + c] = f2b(f3[c]);
    }
    *(short8*)(xb + base) = s0;
    *(short8*)(xb + base + 8) = s1;
}

// ---------------- weights: fp32 [R][C] -> bf16 [C][R] (per expert slab) ----------------
// 64x64 tile via LDS; reads and writes both coalesced.
__global__ __launch_bounds__(256) void tconv_kernel(const float* __restrict__ in,
                                                    short* __restrict__ outp, int R, int C) {
    __shared__ short t[64][72];
    size_t slab = (size_t)R * C;
    const float* ip = in + (size_t)blockIdx.z * slab + (size_t)(blockIdx.y * 64) * C + blockIdx.x * 64;
    short* op = outp + (size_t)blockIdx.z * slab + (size_t)(blockIdx.x * 64) * R + blockIdx.y * 64;
    int tid = threadIdx.x;
    int r = tid >> 2, c4 = (tid & 3) * 16;
    const float* p = ip + (size_t)r * C + c4;
    float4v f0 = *(const float4v*)(p);
    float4v f1 = *(const float4v*)(p + 4);
    float4v f2 = *(const float4v*)(p + 8);
    float4v f3 = *(const float4v*)(p + 12);
#pragma unroll
    for (int j = 0; j < 4; ++j) {
        t[c4 + j][r]      = f2b(f0[j]);
        t[c4 + 4 + j][r]  = f2b(f1[j]);
        t[c4 + 8 + j][r]  = f2b(f2[j]);
        t[c4 + 12 + j][r] = f2b(f3[j]);
    }
    __syncthreads();
    short* q = op + (size_t)r * R + c4;
    *(short8*)q       = *(const short8*)&t[r][c4];
    *(short8*)(q + 8) = *(const short8*)&t[r][c4 + 8];
}

// ---------------- grouped GEMM1 (bf16 weights): h = gelu(xb_gathered @ w1b^T) ----------------
// w1b layout: [e][n=f][k=d]  -> both A and B stages are pure short8 copies.
__global__ __launch_bounds__(256) void gemm1_bf16(const short* __restrict__ xb,
                                                  const short* __restrict__ w1b,
                                                  const int* __restrict__ sorted,
                                                  const int* __restrict__ tmap,
                                                  short* __restrict__ hbuf) {
    __shared__ short As[BM * LDK];
    __shared__ short Bs[BN * LDK];
    __shared__ int srow[BM];
    int mt = blockIdx.y;
    int m_count = tmap[mt * 3 + 2];
    if (m_count == 0) return;
    int e = tmap[mt * 3 + 0];
    int row0 = tmap[mt * 3 + 1];
    int n0 = blockIdx.x * BN;
    int tid = threadIdx.x;
    if (tid < BM) srow[tid] = sorted[row0 + (tid < m_count ? tid : m_count - 1)];
    __syncthreads();

    int lane = tid & 63, wave = tid >> 6;
    int wm = (wave & 1) * 64, wn = (wave >> 1) * 64;
    float4v acc[4][4];
#pragma unroll
    for (int i = 0; i < 4; ++i)
#pragma unroll
        for (int j = 0; j < 4; ++j) acc[i][j] = (float4v)(0.f);

    int r2 = tid >> 1;               // row 0..127 (A: token row, B: n-col row)
    int c2 = (tid & 1) * 16;         // k-offset 0/16
    const short* abase = xb + (size_t)srow[r2] * D_DIM + c2;
    const short* bbase = w1b + (size_t)e * D_DIM * F_DIM + (size_t)(n0 + r2) * D_DIM + c2;

    for (int k0 = 0; k0 < D_DIM; k0 += BK) {
        *(short8*)(&As[r2 * LDK + c2])     = *(const short8*)(abase + k0);
        *(short8*)(&As[r2 * LDK + c2 + 8]) = *(const short8*)(abase + k0 + 8);
        *(short8*)(&Bs[r2 * LDK + c2])     = *(const short8*)(bbase + k0);
        *(short8*)(&Bs[r2 * LDK + c2 + 8]) = *(const short8*)(bbase + k0 + 8);
        __syncthreads();
        short8 af[4], bf[4];
#pragma unroll
        for (int i = 0; i < 4; ++i)
            af[i] = *(const short8*)(&As[(wm + i * 16 + (lane & 15)) * LDK + (lane >> 4) * 8]);
#pragma unroll
        for (int j = 0; j < 4; ++j)
            bf[j] = *(const short8*)(&Bs[(wn + j * 16 + (lane & 15)) * LDK + (lane >> 4) * 8]);
#pragma unroll
        for (int i = 0; i < 4; ++i)
#pragma unroll
            for (int j = 0; j < 4; ++j)
                acc[i][j] = __builtin_amdgcn_mfma_f32_16x16x32_bf16(af[i], bf[j], acc[i][j], 0, 0, 0);
        __syncthreads();
    }
    int rbase = (lane >> 4) * 4;
    int cbase = lane & 15;
#pragma unroll
    for (int i = 0; i < 4; ++i) {
#pragma unroll
        for (int r = 0; r < 4; ++r) {
            int row = wm + i * 16 + rbase + r;
            if (row < m_count) {
                short* hp = hbuf + (size_t)(row0 + row) * F_DIM + n0 + wn + cbase;
#pragma unroll
                for (int j = 0; j < 4; ++j) {
                    float s = acc[i][j][r];
                    float g = 0.5f * s * (1.f + erff(s * 0.70710678118f));
                    hp[j * 16] = f2b(g);
                }
            }
        }
    }
}

// ---------------- grouped GEMM2 (bf16 weights, split-K): out += h @ w2b^T ----------------
// w2b layout: [e][n=d][k=f]; KSPLIT blocks accumulate via fp32 atomics into zeroed out.
__global__ __launch_bounds__(256) void gemm2_bf16(const short* __restrict__ hbuf,
                                                  const short* __restrict__ w2b,
                                                  const int* __restrict__ sorted,
                                                  const int* __restrict__ tmap,
                                                  float* __restrict__ out) {
    __shared__ short As[BM * LDK];
    __shared__ short Bs[BN * LDK];
    __shared__ int srow[BM];
    int mt = blockIdx.y;
    int m_count = tmap[mt * 3 + 2];
    if (m_count == 0) return;
    int e = tmap[mt * 3 + 0];
    int row0 = tmap[mt * 3 + 1];
    int n0 = blockIdx.x * BN;
    int ks0 = blockIdx.z * (F_DIM / KSPLIT);
    int tid = threadIdx.x;
    if (tid < BM) srow[tid] = sorted[row0 + (tid < m_count ? tid : m_count - 1)];
    __syncthreads();

    int lane = tid & 63, wave = tid >> 6;
    int wm = (wave & 1) * 64, wn = (wave >> 1) * 64;
    float4v acc[4][4];
#pragma unroll
    for (int i = 0; i < 4; ++i)
#pragma unroll
        for (int j = 0; j < 4; ++j) acc[i][j] = (float4v)(0.f);

    int r2 = tid >> 1;
    int c2 = (tid & 1) * 16;
    int arc = r2 < m_count ? r2 : m_count - 1;    // clamp: don't read past valid h rows
    const short* abase = hbuf + (size_t)(row0 + arc) * F_DIM + c2 + ks0;
    const short* bbase = w2b + (size_t)e * F_DIM * D_DIM + (size_t)(n0 + r2) * F_DIM + c2 + ks0;

    for (int k0 = 0; k0 < F_DIM / KSPLIT; k0 += BK) {
        *(short8*)(&As[r2 * LDK + c2])     = *(const short8*)(abase + k0);
        *(short8*)(&As[r2 * LDK + c2 + 8]) = *(const short8*)(abase + k0 + 8);
        *(short8*)(&Bs[r2 * LDK + c2])     = *(const short8*)(bbase + k0);
        *(short8*)(&Bs[r2 * LDK + c2 + 8]) = *(const short8*)(bbase + k0 + 8);
        __syncthreads();
        short8 af[4], bf[4];
#pragma unroll
        for (int i = 0; i < 4; ++i)
            af[i] = *(const short8*)(&As[(wm + i * 16 + (lane & 15)) * LDK + (lane >> 4) * 8]);
#pragma unroll
        for (int j = 0; j < 4; ++j)
            bf[j] = *(const short8*)(&Bs[(wn + j * 16 + (lane & 15)) * LDK + (lane >> 4) * 8]);
#pragma unroll
        for (int i = 0; i < 4; ++i)
#pragma unroll
            for (int j = 0; j < 4; ++j)
                acc[i][j] = __builtin_amdgcn_mfma_f32_16x16x32_bf16(af[i], bf[j], acc[i][j], 0, 0, 0);
        __syncthreads();
    }
    int rbase = (lane >> 4) * 4;
    int cbase = lane & 15;
#pragma unroll
    for (int i = 0; i < 4; ++i) {
#pragma unroll
        for (int r = 0; r < 4; ++r) {
            int row = wm + i * 16 + rbase + r;
            if (row < m_count) {
                float* op = out + (size_t)srow[row] * D_DIM + n0 + wn + cbase;
#pragma unroll
                for (int j = 0; j < 4; ++j) atomicAdd(op + j * 16, acc[i][j][r]);
            }
        }
    }
}

// ================= legacy fp32-weight path (fallback if workspace too small) =================
__global__ __launch_bounds__(256) void gemm1_kernel(const float* __restrict__ x,
                                                    const float* __restrict__ w1,
                                                    const int* __restrict__ sorted,
                                                    const int* __restrict__ tmap,
                                                    short* __restrict__ hbuf) {
    __shared__ short As[BM * LDK];
    __shared__ short Bs[BN * LDK];
    __shared__ int srow[BM];
    int mt = blockIdx.y;
    int m_count = tmap[mt * 3 + 2];
    if (m_count == 0) return;
    int e = tmap[mt * 3 + 0];
    int row0 = tmap[mt * 3 + 1];
    int n0 = blockIdx.x * BN;
    int tid = threadIdx.x;
    if (tid < BM) srow[tid] = sorted[row0 + (tid < m_count ? tid : m_count - 1)];
    __syncthreads();

    int lane = tid & 63, wave = tid >> 6;
    int wm = (wave & 1) * 64, wn = (wave >> 1) * 64;
    float4v acc[4][4];
#pragma unroll
    for (int i = 0; i < 4; ++i)
#pragma unroll
        for (int j = 0; j < 4; ++j) acc[i][j] = (float4v)(0.f);

    int ar = tid >> 1;
    int ac = (tid & 1) * 16;
    int bn = tid & 127;
    int bq = (tid >> 7) * 16;
    const float* abase = x + (size_t)srow[ar] * D_DIM + ac;
    const float* bbase = w1 + (size_t)e * D_DIM * F_DIM + (size_t)bq * F_DIM + (n0 + bn);

    for (int k0 = 0; k0 < D_DIM; k0 += BK) {
        {
            const float* ap = abase + k0;
            float4v f0 = *(const float4v*)(ap);
            float4v f1 = *(const float4v*)(ap + 4);
            float4v f2 = *(const float4v*)(ap + 8);
            float4v f3 = *(const float4v*)(ap + 12);
            short8 s0, s1;
#pragma unroll
            for (int c = 0; c < 4; ++c) {
                s0[c] = f2b(f0[c]); s0[4 + c] = f2b(f1[c]);
                s1[c] = f2b(f2[c]); s1[4 + c] = f2b(f3[c]);
            }
            *(short8*)(&As[ar * LDK + ac]) = s0;
            *(short8*)(&As[ar * LDK + ac + 8]) = s1;
        }
        {
            const float* bp = bbase + (size_t)k0 * F_DIM;
            float v[16];
#pragma unroll
            for (int j = 0; j < 16; ++j) v[j] = bp[(size_t)j * F_DIM];
            short8 s0, s1;
#pragma unroll
            for (int j = 0; j < 8; ++j) { s0[j] = f2b(v[j]); s1[j] = f2b(v[8 + j]); }
            *(short8*)(&Bs[bn * LDK + bq]) = s0;
            *(short8*)(&Bs[bn * LDK + bq + 8]) = s1;
        }
        __syncthreads();
        short8 af[4], bf[4];
#pragma unroll
        for (int i = 0; i < 4; ++i)
            af[i] = *(const short8*)(&As[(wm + i * 16 + (lane & 15)) * LDK + (lane >> 4) * 8]);
#pragma unroll
        for (int j = 0; j < 4; ++j)
            bf[j] = *(const short8*)(&Bs[(wn + j * 16 + (lane & 15)) * LDK + (lane >> 4) * 8]);
#pragma unroll
        for (int i = 0; i < 4; ++i)
#pragma unroll
            for (int j = 0; j < 4; ++j)
                acc[i][j] = __builtin_amdgcn_mfma_f32_16x16x32_bf16(af[i], bf[j], acc[i][j], 0, 0, 0);
        __syncthreads();
    }
    int rbase = (lane >> 4) * 4;
    int cbase = lane & 15;
#pragma unroll
    for (int i = 0; i < 4; ++i) {
#pragma unroll
        for (int r = 0; r < 4; ++r) {
            int row = wm + i * 16 + rbase + r;
            if (row < m_count) {
                short* hp = hbuf + (size_t)(row0 + row) * F_DIM + n0 + wn + cbase;
#pragma unroll
                for (int j = 0; j < 4; ++j) {
                    float s = acc[i][j][r];
                    float g = 0.5f * s * (1.f + erff(s * 0.70710678118f));
                    hp[j * 16] = f2b(g);
                }
            }
        }
    }
}

__global__ __launch_bounds__(256) void gemm2_kernel(const short* __restrict__ hbuf,
                                                    const float* __restrict__ w2,
                                                    const int* __restrict__ sorted,
                                                    const int* __restrict__ tmap,
                                                    float* __restrict__ out) {
    __shared__ short As[BM * LDK];
    __shared__ short Bs[BN * LDK];
    __shared__ int srow[BM];
    int mt = blockIdx.y;
    int m_count = tmap[mt * 3 + 2];
    if (m_count == 0) return;
    int e = tmap[mt * 3 + 0];
    int row0 = tmap[mt * 3 + 1];
    int n0 = blockIdx.x * BN;
    int tid = threadIdx.x;
    if (tid < BM) srow[tid] = sorted[row0 + (tid < m_count ? tid : m_count - 1)];
    __syncthreads();

    int lane = tid & 63, wave = tid >> 6;
    int wm = (wave & 1) * 64, wn = (wave >> 1) * 64;
    float4v acc[4][4];
#pragma unroll
    for (int i = 0; i < 4; ++i)
#pragma unroll
        for (int j = 0; j < 4; ++j) acc[i][j] = (float4v)(0.f);

    int ar = tid >> 1;
    int ac = (tid & 1) * 16;
    int bn = tid & 127;
    int bq = (tid >> 7) * 16;
    int arc = ar < m_count ? ar : m_count - 1;
    const short* abase = hbuf + (size_t)(row0 + arc) * F_DIM + ac;
    const float* bbase = w2 + (size_t)e * F_DIM * D_DIM + (size_t)bq * D_DIM + (n0 + bn);

    for (int k0 = 0; k0 < F_DIM; k0 += BK) {
        {
            const short* ap = abase + k0;
            *(short8*)(&As[ar * LDK + ac]) = *(const short8*)(ap);
            *(short8*)(&As[ar * LDK + ac + 8]) = *(const short8*)(ap + 8);
        }
        {
            const float* bp = bbase + (size_t)k0 * D_DIM;
            float v[16];
#pragma unroll
            for (int j = 0; j < 16; ++j) v[j] = bp[(size_t)j * D_DIM];
            short8 s0, s1;
#pragma unroll
            for (int j = 0; j < 8; ++j) { s0[j] = f2b(v[j]); s1[j] = f2b(v[8 + j]); }
            *(short8*)(&Bs[bn * LDK + bq]) = s0;
            *(short8*)(&Bs[bn * LDK + bq + 8]) = s1;
        }
        __syncthreads();
        short8 af[4], bf[4];
#pragma unroll
        for (int i = 0; i < 4; ++i)
            af[i] = *(const short8*)(&As[(wm + i * 16 + (lane & 15)) * LDK + (lane >> 4) * 8]);
#pragma unroll
        for (int j = 0; j < 4; ++j)
            bf[j] = *(const short8*)(&Bs[(wn + j * 16 + (lane & 15)) * LDK + (lane >> 4) * 8]);
#pragma unroll
        for (int i = 0; i < 4; ++i)
#pragma unroll
            for (int j = 0; j < 4; ++j)
                acc[i][j] = __builtin_amdgcn_mfma_f32_16x16x32_bf16(af[i], bf[j], acc[i][j], 0, 0, 0);
        __syncthreads();
    }
    int rbase = (lane >> 4) * 4;
    int cbase = lane & 15;
#pragma unroll
    for (int i = 0; i < 4; ++i) {
#pragma unroll
        for (int r = 0; r < 4; ++r) {
            int row = wm + i * 16 + rbase + r;
            if (row < m_count) {
                float* op = out + (size_t)srow[row] * D_DIM + n0 + wn + cbase;
#pragma unroll
                for (int j = 0; j < 4; ++j) op[j * 16] = acc[i][j][r];
            }
        }
    }
}

extern "C" void kernel_launch(void* const* d_in, const int* in_sizes, int n_in,
                              void* d_out, int out_size, void* d_ws, size_t ws_size,
                              hipStream_t stream) {
    const float* x  = (const float*)d_in[0];
    const float* gw = (const float*)d_in[1];
    const float* w1 = (const float*)d_in[2];
    const float* w2 = (const float*)d_in[3];
    float* out = (float*)d_out;
    char* ws = (char*)d_ws;

    int* counts  = (int*)(ws);            // 8 ints
    int* offsets = (int*)(ws + 64);       // 9 ints
    int* tmap    = (int*)(ws + 128);      // 40*3 ints
    int* eid     = (int*)(ws + 1024);     // 4096 ints
    int* rnk     = (int*)(ws + 17408);    // 4096 ints
    int* sorted  = (int*)(ws + 33792);    // 4096 ints
    short* hbuf  = (short*)(ws + 51200);  // 4096*4096 bf16 = 33.55 MB

    const size_t HB  = 33554432ull;       // hbuf bytes
    const size_t XB  = 8388608ull;        // xb bytes  (4096*1024*2)
    const size_t WB  = 67108864ull;       // w1b/w2b bytes each (8*1024*4096*2)
    short* xb  = (short*)(ws + 51200 + HB);
    short* w1b = (short*)(ws + 51200 + HB + XB);
    short* w2b = (short*)(ws + 51200 + HB + XB + WB);
    const size_t need = 51200ull + HB + XB + 2ull * WB;   // ~176.2 MB
    bool fast = ws_size >= need;

    hipMemsetAsync(counts, 0, 32, stream);
    router_kernel<<<T_TOK / 4, 256, 0, stream>>>(x, gw, eid, rnk, counts);

    if (fast) {
        hipMemsetAsync(out, 0, (size_t)T_TOK * D_DIM * 4, stream);
        cvt_x_kernel<<<T_TOK * D_DIM / (256 * 16), 256, 0, stream>>>(x, xb);
        // w1: [e][d=1024][f=4096] -> w1b [e][f][d]
        tconv_kernel<<<dim3(F_DIM / 64, D_DIM / 64, E_EXP), 256, 0, stream>>>(w1, w1b, D_DIM, F_DIM);
        // w2: [e][f=4096][d=1024] -> w2b [e][d][f]
        tconv_kernel<<<dim3(D_DIM / 64, F_DIM / 64, E_EXP), 256, 0, stream>>>(w2, w2b, F_DIM, D_DIM);
    }

    prefix_kernel<<<1, 1, 0, stream>>>(counts, offsets, tmap);
    scatter_kernel<<<T_TOK / 256, 256, 0, stream>>>(eid, rnk, offsets, sorted);

    if (fast) {
        gemm1_bf16<<<dim3(F_DIM / BN, MAX_TILES), 256, 0, stream>>>(xb, w1b, sorted, tmap, hbuf);
        gemm2_bf16<<<dim3(D_DIM / BN, MAX_TILES, KSPLIT), 256, 0, stream>>>(hbuf, w2b, sorted, tmap, out);
    } else {
        gemm1_kernel<<<dim3(F_DIM / BN, MAX_TILES), 256, 0, stream>>>(x, w1, sorted, tmap, hbuf);
        gemm2_kernel<<<dim3(D_DIM / BN, MAX_TILES), 256, 0, stream>>>(hbuf, w2, sorted, tmap, out);
    }
}

// Round 2
// 554.458 us; speedup vs baseline: 1.0281x; 1.0281x over previous
//
#include <hip/hip_runtime.h>
#include <math.h>

#define T_TOK 4096
#define D_DIM 1024
#define E_EXP 8
#define F_DIM 4096
#define BM 128
#define BN 128
#define BK 32
#define LDK 40          // legacy fallback pad
#define MAX_TILES 40    // sum_e ceil(cnt_e/128) <= 4096/128 + 7 = 39
#define KSPLIT 4        // gemm2 split-K factor (occupancy fix)

typedef __attribute__((ext_vector_type(8))) short short8;
typedef __attribute__((ext_vector_type(4))) float float4v;

__device__ __forceinline__ short f2b(float f) {
    union { float f; unsigned u; } v; v.f = f;
    unsigned r = v.u + 0x7fffu + ((v.u >> 16) & 1u);   // RNE to bf16
    return (short)(r >> 16);
}

// async 16B global -> LDS (wave-uniform LDS base + lane*16, per-lane global src)
__device__ __forceinline__ void gll16(const short* g, short* l) {
    __builtin_amdgcn_global_load_lds((const __attribute__((address_space(1))) unsigned*)g,
                                     (__attribute__((address_space(3))) unsigned*)l, 16, 0, 0);
}

// ---------------- router: fp32 logits + argmax (exact routing) ----------------
__global__ void router_kernel(const float* __restrict__ x, const float* __restrict__ gw,
                              int* __restrict__ eid, int* __restrict__ rnk,
                              int* __restrict__ counts) {
    int lane = threadIdx.x & 63;
    int wave = threadIdx.x >> 6;
    int t = blockIdx.x * 4 + wave;
    const float* xr = x + (size_t)t * D_DIM;
    float p[E_EXP];
#pragma unroll
    for (int e = 0; e < E_EXP; ++e) p[e] = 0.f;
#pragma unroll
    for (int i = 0; i < D_DIM / 64; ++i) {
        float v = xr[lane + 64 * i];
#pragma unroll
        for (int e = 0; e < E_EXP; ++e)
            p[e] = fmaf(v, gw[e * D_DIM + lane + 64 * i], p[e]);
    }
#pragma unroll
    for (int off = 32; off > 0; off >>= 1) {
#pragma unroll
        for (int e = 0; e < E_EXP; ++e) p[e] += __shfl_down(p[e], off, 64);
    }
    if (lane == 0) {
        int best = 0; float bv = p[0];
#pragma unroll
        for (int e = 1; e < E_EXP; ++e) if (p[e] > bv) { bv = p[e]; best = e; }
        eid[t] = best;
        rnk[t] = atomicAdd(&counts[best], 1);
    }
}

// ---------------- prefix + tile map (trivial, E=8) ----------------
__global__ void prefix_kernel(const int* __restrict__ counts, int* __restrict__ offsets,
                              int* __restrict__ tmap) {
    int off = 0;
    offsets[0] = 0;
    int nt = 0;
    for (int e = 0; e < E_EXP; ++e) {
        int c = counts[e];
        for (int m0 = 0; m0 < c; m0 += BM) {
            tmap[nt * 3 + 0] = e;
            tmap[nt * 3 + 1] = off + m0;
            tmap[nt * 3 + 2] = (c - m0 < BM) ? (c - m0) : BM;
            ++nt;
        }
        off += c;
        offsets[e + 1] = off;
    }
    for (; nt < MAX_TILES; ++nt) tmap[nt * 3 + 2] = 0;
}

__global__ void scatter_kernel(const int* __restrict__ eid, const int* __restrict__ rnk,
                               const int* __restrict__ offsets, int* __restrict__ sorted) {
    int t = blockIdx.x * 256 + threadIdx.x;
    sorted[offsets[eid[t]] + rnk[t]] = t;
}

// ---------------- x: fp32 -> bf16, same layout ----------------
__global__ __launch_bounds__(256) void cvt_x_kernel(const float* __restrict__ x,
                                                    short* __restrict__ xb) {
    size_t base = ((size_t)blockIdx.x * 256 + threadIdx.x) * 16;
    float4v f0 = *(const float4v*)(x + base);
    float4v f1 = *(const float4v*)(x + base + 4);
    float4v f2 = *(const float4v*)(x + base + 8);
    float4v f3 = *(const float4v*)(x + base + 12);
    short8 s0, s1;
#pragma unroll
    for (int c = 0; c < 4; ++c) {
        s0[c] = f2b(f0[c]); s0[4 + c] = f2b(f1[c]);
        s1[c] = f2b(f2[c]); s1[4 + c] = f2b(f3[c]);
    }
    *(short8*)(xb + base) = s0;
    *(short8*)(xb + base + 8) = s1;
}

// ---------------- weights: fp32 [R][C] -> bf16 [C][R] (per expert slab) ----------------
__global__ __launch_bounds__(256) void tconv_kernel(const float* __restrict__ in,
                                                    short* __restrict__ outp, int R, int C) {
    __shared__ short t[64][72];
    size_t slab = (size_t)R * C;
    const float* ip = in + (size_t)blockIdx.z * slab + (size_t)(blockIdx.y * 64) * C + blockIdx.x * 64;
    short* op = outp + (size_t)blockIdx.z * slab + (size_t)(blockIdx.x * 64) * R + blockIdx.y * 64;
    int tid = threadIdx.x;
    int r = tid >> 2, c4 = (tid & 3) * 16;
    const float* p = ip + (size_t)r * C + c4;
    float4v f0 = *(const float4v*)(p);
    float4v f1 = *(const float4v*)(p + 4);
    float4v f2 = *(const float4v*)(p + 8);
    float4v f3 = *(const float4v*)(p + 12);
#pragma unroll
    for (int j = 0; j < 4; ++j) {
        t[c4 + j][r]      = f2b(f0[j]);
        t[c4 + 4 + j][r]  = f2b(f1[j]);
        t[c4 + 8 + j][r]  = f2b(f2[j]);
        t[c4 + 12 + j][r] = f2b(f3[j]);
    }
    __syncthreads();
    short* q = op + (size_t)r * R + c4;
    *(short8*)q       = *(const short8*)&t[r][c4];
    *(short8*)(q + 8) = *(const short8*)&t[r][c4 + 8];
}

// ============ grouped GEMM1, m97-structure: global_load_lds + swizzled linear LDS ============
// w1b layout: [e][n=f][k=d]. LDS [row][BK=32] bf16, 16B chunk c stored at c ^ ((row>>1)&3).
__global__ __launch_bounds__(256) void gemm1_bf16(const short* __restrict__ xb,
                                                  const short* __restrict__ w1b,
                                                  const int* __restrict__ sorted,
                                                  const int* __restrict__ tmap,
                                                  short* __restrict__ hbuf) {
    __shared__ short As[BM * BK];
    __shared__ short Bs[BN * BK];
    __shared__ int srow[BM];
    int mt = blockIdx.y;
    int m_count = tmap[mt * 3 + 2];
    if (m_count == 0) return;
    int e = tmap[mt * 3 + 0];
    int row0 = tmap[mt * 3 + 1];
    int n0 = blockIdx.x * BN;
    int tid = threadIdx.x;
    if (tid < BM) srow[tid] = sorted[row0 + (tid < m_count ? tid : m_count - 1)];
    __syncthreads();

    int lane = tid & 63, wave = tid >> 6;
    int wm = (wave & 1) * 64, wn = (wave >> 1) * 64;
    float4v acc[4][4];
#pragma unroll
    for (int i = 0; i < 4; ++i)
#pragma unroll
        for (int j = 0; j < 4; ++j) acc[i][j] = (float4v)(0.f);

    // staging geometry: chunk q = wave (rows q*16..q*16+15) and q = wave+4
    int r0 = wave * 16 + (lane >> 2);
    int r1 = r0 + 64;
    int p0 = (((lane & 3) ^ ((r0 >> 1) & 3)) * 8);   // swizzled source chunk (elems)
    int p1 = (((lane & 3) ^ ((r1 >> 1) & 3)) * 8);
    const short* ag0 = xb + (size_t)srow[r0] * D_DIM + p0;
    const short* ag1 = xb + (size_t)srow[r1] * D_DIM + p1;
    const short* wbase = w1b + (size_t)e * D_DIM * F_DIM;
    const short* bg0 = wbase + (size_t)(n0 + r0) * D_DIM + p0;
    const short* bg1 = wbase + (size_t)(n0 + r1) * D_DIM + p1;
    short* lA0 = As + wave * 512;          // wave-uniform LDS bases (bytes: wave*1024)
    short* lA1 = As + wave * 512 + 2048;
    short* lB0 = Bs + wave * 512;
    short* lB1 = Bs + wave * 512 + 2048;

    int rfa = lane & 15;        // fragment row within 16
    int clog = lane >> 4;       // logical 16B chunk 0..3

    for (int k0 = 0; k0 < D_DIM; k0 += BK) {
        gll16(ag0 + k0, lA0);
        gll16(ag1 + k0, lA1);
        gll16(bg0 + k0, lB0);
        gll16(bg1 + k0, lB1);
        __syncthreads();        // drains vmcnt -> staged data visible
        short8 af[4], bfr[4];
#pragma unroll
        for (int i = 0; i < 4; ++i) {
            int row = wm + i * 16 + rfa;
            af[i] = *(const short8*)(&As[row * BK + ((clog ^ ((row >> 1) & 3)) * 8)]);
        }
#pragma unroll
        for (int j = 0; j < 4; ++j) {
            int row = wn + j * 16 + rfa;
            bfr[j] = *(const short8*)(&Bs[row * BK + ((clog ^ ((row >> 1) & 3)) * 8)]);
        }
#pragma unroll
        for (int i = 0; i < 4; ++i)
#pragma unroll
            for (int j = 0; j < 4; ++j)
                acc[i][j] = __builtin_amdgcn_mfma_f32_16x16x32_bf16(af[i], bfr[j], acc[i][j], 0, 0, 0);
        __syncthreads();        // protect LDS before next-stage overwrite
    }
    int rbase = (lane >> 4) * 4;
    int cbase = lane & 15;
#pragma unroll
    for (int i = 0; i < 4; ++i) {
#pragma unroll
        for (int r = 0; r < 4; ++r) {
            int row = wm + i * 16 + rbase + r;
            if (row < m_count) {
                short* hp = hbuf + (size_t)(row0 + row) * F_DIM + n0 + wn + cbase;
#pragma unroll
                for (int j = 0; j < 4; ++j) {
                    float s = acc[i][j][r];
                    float g = 0.5f * s * (1.f + erff(s * 0.70710678118f));
                    hp[j * 16] = f2b(g);
                }
            }
        }
    }
}

// ============ grouped GEMM2, m97-structure + split-K atomics ============
// w2b layout: [e][n=d][k=f].
__global__ __launch_bounds__(256) void gemm2_bf16(const short* __restrict__ hbuf,
                                                  const short* __restrict__ w2b,
                                                  const int* __restrict__ sorted,
                                                  const int* __restrict__ tmap,
                                                  float* __restrict__ out) {
    __shared__ short As[BM * BK];
    __shared__ short Bs[BN * BK];
    __shared__ int srow[BM];
    int mt = blockIdx.y;
    int m_count = tmap[mt * 3 + 2];
    if (m_count == 0) return;
    int e = tmap[mt * 3 + 0];
    int row0 = tmap[mt * 3 + 1];
    int n0 = blockIdx.x * BN;
    int ks0 = blockIdx.z * (F_DIM / KSPLIT);
    int tid = threadIdx.x;
    if (tid < BM) srow[tid] = sorted[row0 + (tid < m_count ? tid : m_count - 1)];
    __syncthreads();

    int lane = tid & 63, wave = tid >> 6;
    int wm = (wave & 1) * 64, wn = (wave >> 1) * 64;
    float4v acc[4][4];
#pragma unroll
    for (int i = 0; i < 4; ++i)
#pragma unroll
        for (int j = 0; j < 4; ++j) acc[i][j] = (float4v)(0.f);

    int r0 = wave * 16 + (lane >> 2);
    int r1 = r0 + 64;
    int p0 = (((lane & 3) ^ ((r0 >> 1) & 3)) * 8);
    int p1 = (((lane & 3) ^ ((r1 >> 1) & 3)) * 8);
    int cr0 = r0 < m_count ? r0 : m_count - 1;     // clamp source rows of h
    int cr1 = r1 < m_count ? r1 : m_count - 1;
    const short* ag0 = hbuf + (size_t)(row0 + cr0) * F_DIM + ks0 + p0;
    const short* ag1 = hbuf + (size_t)(row0 + cr1) * F_DIM + ks0 + p1;
    const short* wbase = w2b + (size_t)e * F_DIM * D_DIM;
    const short* bg0 = wbase + (size_t)(n0 + r0) * F_DIM + ks0 + p0;
    const short* bg1 = wbase + (size_t)(n0 + r1) * F_DIM + ks0 + p1;
    short* lA0 = As + wave * 512;
    short* lA1 = As + wave * 512 + 2048;
    short* lB0 = Bs + wave * 512;
    short* lB1 = Bs + wave * 512 + 2048;

    int rfa = lane & 15;
    int clog = lane >> 4;

    for (int k0 = 0; k0 < F_DIM / KSPLIT; k0 += BK) {
        gll16(ag0 + k0, lA0);
        gll16(ag1 + k0, lA1);
        gll16(bg0 + k0, lB0);
        gll16(bg1 + k0, lB1);
        __syncthreads();
        short8 af[4], bfr[4];
#pragma unroll
        for (int i = 0; i < 4; ++i) {
            int row = wm + i * 16 + rfa;
            af[i] = *(const short8*)(&As[row * BK + ((clog ^ ((row >> 1) & 3)) * 8)]);
        }
#pragma unroll
        for (int j = 0; j < 4; ++j) {
            int row = wn + j * 16 + rfa;
            bfr[j] = *(const short8*)(&Bs[row * BK + ((clog ^ ((row >> 1) & 3)) * 8)]);
        }
#pragma unroll
        for (int i = 0; i < 4; ++i)
#pragma unroll
            for (int j = 0; j < 4; ++j)
                acc[i][j] = __builtin_amdgcn_mfma_f32_16x16x32_bf16(af[i], bfr[j], acc[i][j], 0, 0, 0);
        __syncthreads();
    }
    int rbase = (lane >> 4) * 4;
    int cbase = lane & 15;
#pragma unroll
    for (int i = 0; i < 4; ++i) {
#pragma unroll
        for (int r = 0; r < 4; ++r) {
            int row = wm + i * 16 + rbase + r;
            if (row < m_count) {
                float* op = out + (size_t)srow[row] * D_DIM + n0 + wn + cbase;
#pragma unroll
                for (int j = 0; j < 4; ++j) atomicAdd(op + j * 16, acc[i][j][r]);
            }
        }
    }
}

// ================= legacy fp32-weight path (fallback if workspace too small) =================
__global__ __launch_bounds__(256) void gemm1_kernel(const float* __restrict__ x,
                                                    const float* __restrict__ w1,
                                                    const int* __restrict__ sorted,
                                                    const int* __restrict__ tmap,
                                                    short* __restrict__ hbuf) {
    __shared__ short As[BM * LDK];
    __shared__ short Bs[BN * LDK];
    __shared__ int srow[BM];
    int mt = blockIdx.y;
    int m_count = tmap[mt * 3 + 2];
    if (m_count == 0) return;
    int e = tmap[mt * 3 + 0];
    int row0 = tmap[mt * 3 + 1];
    int n0 = blockIdx.x * BN;
    int tid = threadIdx.x;
    if (tid < BM) srow[tid] = sorted[row0 + (tid < m_count ? tid : m_count - 1)];
    __syncthreads();

    int lane = tid & 63, wave = tid >> 6;
    int wm = (wave & 1) * 64, wn = (wave >> 1) * 64;
    float4v acc[4][4];
#pragma unroll
    for (int i = 0; i < 4; ++i)
#pragma unroll
        for (int j = 0; j < 4; ++j) acc[i][j] = (float4v)(0.f);

    int ar = tid >> 1;
    int ac = (tid & 1) * 16;
    int bn = tid & 127;
    int bq = (tid >> 7) * 16;
    const float* abase = x + (size_t)srow[ar] * D_DIM + ac;
    const float* bbase = w1 + (size_t)e * D_DIM * F_DIM + (size_t)bq * F_DIM + (n0 + bn);

    for (int k0 = 0; k0 < D_DIM; k0 += BK) {
        {
            const float* ap = abase + k0;
            float4v f0 = *(const float4v*)(ap);
            float4v f1 = *(const float4v*)(ap + 4);
            float4v f2 = *(const float4v*)(ap + 8);
            float4v f3 = *(const float4v*)(ap + 12);
            short8 s0, s1;
#pragma unroll
            for (int c = 0; c < 4; ++c) {
                s0[c] = f2b(f0[c]); s0[4 + c] = f2b(f1[c]);
                s1[c] = f2b(f2[c]); s1[4 + c] = f2b(f3[c]);
            }
            *(short8*)(&As[ar * LDK + ac]) = s0;
            *(short8*)(&As[ar * LDK + ac + 8]) = s1;
        }
        {
            const float* bp = bbase + (size_t)k0 * F_DIM;
            float v[16];
#pragma unroll
            for (int j = 0; j < 16; ++j) v[j] = bp[(size_t)j * F_DIM];
            short8 s0, s1;
#pragma unroll
            for (int j = 0; j < 8; ++j) { s0[j] = f2b(v[j]); s1[j] = f2b(v[8 + j]); }
            *(short8*)(&Bs[bn * LDK + bq]) = s0;
            *(short8*)(&Bs[bn * LDK + bq + 8]) = s1;
        }
        __syncthreads();
        short8 af[4], bfr[4];
#pragma unroll
        for (int i = 0; i < 4; ++i)
            af[i] = *(const short8*)(&As[(wm + i * 16 + (lane & 15)) * LDK + (lane >> 4) * 8]);
#pragma unroll
        for (int j = 0; j < 4; ++j)
            bfr[j] = *(const short8*)(&Bs[(wn + j * 16 + (lane & 15)) * LDK + (lane >> 4) * 8]);
#pragma unroll
        for (int i = 0; i < 4; ++i)
#pragma unroll
            for (int j = 0; j < 4; ++j)
                acc[i][j] = __builtin_amdgcn_mfma_f32_16x16x32_bf16(af[i], bfr[j], acc[i][j], 0, 0, 0);
        __syncthreads();
    }
    int rbase = (lane >> 4) * 4;
    int cbase = lane & 15;
#pragma unroll
    for (int i = 0; i < 4; ++i) {
#pragma unroll
        for (int r = 0; r < 4; ++r) {
            int row = wm + i * 16 + rbase + r;
            if (row < m_count) {
                short* hp = hbuf + (size_t)(row0 + row) * F_DIM + n0 + wn + cbase;
#pragma unroll
                for (int j = 0; j < 4; ++j) {
                    float s = acc[i][j][r];
                    float g = 0.5f * s * (1.f + erff(s * 0.70710678118f));
                    hp[j * 16] = f2b(g);
                }
            }
        }
    }
}

__global__ __launch_bounds__(256) void gemm2_kernel(const short* __restrict__ hbuf,
                                                    const float* __restrict__ w2,
                                                    const int* __restrict__ sorted,
                                                    const int* __restrict__ tmap,
                                                    float* __restrict__ out) {
    __shared__ short As[BM * LDK];
    __shared__ short Bs[BN * LDK];
    __shared__ int srow[BM];
    int mt = blockIdx.y;
    int m_count = tmap[mt * 3 + 2];
    if (m_count == 0) return;
    int e = tmap[mt * 3 + 0];
    int row0 = tmap[mt * 3 + 1];
    int n0 = blockIdx.x * BN;
    int tid = threadIdx.x;
    if (tid < BM) srow[tid] = sorted[row0 + (tid < m_count ? tid : m_count - 1)];
    __syncthreads();

    int lane = tid & 63, wave = tid >> 6;
    int wm = (wave & 1) * 64, wn = (wave >> 1) * 64;
    float4v acc[4][4];
#pragma unroll
    for (int i = 0; i < 4; ++i)
#pragma unroll
        for (int j = 0; j < 4; ++j) acc[i][j] = (float4v)(0.f);

    int ar = tid >> 1;
    int ac = (tid & 1) * 16;
    int bn = tid & 127;
    int bq = (tid >> 7) * 16;
    int arc = ar < m_count ? ar : m_count - 1;
    const short* abase = hbuf + (size_t)(row0 + arc) * F_DIM + ac;
    const float* bbase = w2 + (size_t)e * F_DIM * D_DIM + (size_t)bq * D_DIM + (n0 + bn);

    for (int k0 = 0; k0 < F_DIM; k0 += BK) {
        {
            const short* ap = abase + k0;
            *(short8*)(&As[ar * LDK + ac]) = *(const short8*)(ap);
            *(short8*)(&As[ar * LDK + ac + 8]) = *(const short8*)(ap + 8);
        }
        {
            const float* bp = bbase + (size_t)k0 * D_DIM;
            float v[16];
#pragma unroll
            for (int j = 0; j < 16; ++j) v[j] = bp[(size_t)j * D_DIM];
            short8 s0, s1;
#pragma unroll
            for (int j = 0; j < 8; ++j) { s0[j] = f2b(v[j]); s1[j] = f2b(v[8 + j]); }
            *(short8*)(&Bs[bn * LDK + bq]) = s0;
            *(short8*)(&Bs[bn * LDK + bq + 8]) = s1;
        }
        __syncthreads();
        short8 af[4], bfr[4];
#pragma unroll
        for (int i = 0; i < 4; ++i)
            af[i] = *(const short8*)(&As[(wm + i * 16 + (lane & 15)) * LDK + (lane >> 4) * 8]);
#pragma unroll
        for (int j = 0; j < 4; ++j)
            bfr[j] = *(const short8*)(&Bs[(wn + j * 16 + (lane & 15)) * LDK + (lane >> 4) * 8]);
#pragma unroll
        for (int i = 0; i < 4; ++i)
#pragma unroll
            for (int j = 0; j < 4; ++j)
                acc[i][j] = __builtin_amdgcn_mfma_f32_16x16x32_bf16(af[i], bfr[j], acc[i][j], 0, 0, 0);
        __syncthreads();
    }
    int rbase = (lane >> 4) * 4;
    int cbase = lane & 15;
#pragma unroll
    for (int i = 0; i < 4; ++i) {
#pragma unroll
        for (int r = 0; r < 4; ++r) {
            int row = wm + i * 16 + rbase + r;
            if (row < m_count) {
                float* op = out + (size_t)srow[row] * D_DIM + n0 + wn + cbase;
#pragma unroll
                for (int j = 0; j < 4; ++j) op[j * 16] = acc[i][j][r];
            }
        }
    }
}

extern "C" void kernel_launch(void* const* d_in, const int* in_sizes, int n_in,
                              void* d_out, int out_size, void* d_ws, size_t ws_size,
                              hipStream_t stream) {
    const float* x  = (const float*)d_in[0];
    const float* gw = (const float*)d_in[1];
    const float* w1 = (const float*)d_in[2];
    const float* w2 = (const float*)d_in[3];
    float* out = (float*)d_out;
    char* ws = (char*)d_ws;

    int* counts  = (int*)(ws);            // 8 ints
    int* offsets = (int*)(ws + 64);       // 9 ints
    int* tmap    = (int*)(ws + 128);      // 40*3 ints
    int* eid     = (int*)(ws + 1024);     // 4096 ints
    int* rnk     = (int*)(ws + 17408);    // 4096 ints
    int* sorted  = (int*)(ws + 33792);    // 4096 ints
    short* hbuf  = (short*)(ws + 51200);  // 4096*4096 bf16 = 33.55 MB

    const size_t HB  = 33554432ull;       // hbuf bytes
    const size_t XB  = 8388608ull;        // xb bytes  (4096*1024*2)
    const size_t WB  = 67108864ull;       // w1b/w2b bytes each (8*1024*4096*2)
    short* xb  = (short*)(ws + 51200 + HB);
    short* w1b = (short*)(ws + 51200 + HB + XB);
    short* w2b = (short*)(ws + 51200 + HB + XB + WB);
    const size_t need = 51200ull + HB + XB + 2ull * WB;   // ~176.2 MB
    bool fast = ws_size >= need;

    hipMemsetAsync(counts, 0, 32, stream);
    router_kernel<<<T_TOK / 4, 256, 0, stream>>>(x, gw, eid, rnk, counts);

    if (fast) {
        hipMemsetAsync(out, 0, (size_t)T_TOK * D_DIM * 4, stream);
        cvt_x_kernel<<<T_TOK * D_DIM / (256 * 16), 256, 0, stream>>>(x, xb);
        // w1: [e][d=1024][f=4096] -> w1b [e][f][d]
        tconv_kernel<<<dim3(F_DIM / 64, D_DIM / 64, E_EXP), 256, 0, stream>>>(w1, w1b, D_DIM, F_DIM);
        // w2: [e][f=4096][d=1024] -> w2b [e][d][f]
        tconv_kernel<<<dim3(D_DIM / 64, F_DIM / 64, E_EXP), 256, 0, stream>>>(w2, w2b, F_DIM, D_DIM);
    }

    prefix_kernel<<<1, 1, 0, stream>>>(counts, offsets, tmap);
    scatter_kernel<<<T_TOK / 256, 256, 0, stream>>>(eid, rnk, offsets, sorted);

    if (fast) {
        gemm1_bf16<<<dim3(F_DIM / BN, MAX_TILES), 256, 0, stream>>>(xb, w1b, sorted, tmap, hbuf);
        gemm2_bf16<<<dim3(D_DIM / BN, MAX_TILES, KSPLIT), 256, 0, stream>>>(hbuf, w2b, sorted, tmap, out);
    } else {
        gemm1_kernel<<<dim3(F_DIM / BN, MAX_TILES), 256, 0, stream>>>(x, w1, sorted, tmap, hbuf);
        gemm2_kernel<<<dim3(D_DIM / BN, MAX_TILES), 256, 0, stream>>>(hbuf, w2, sorted, tmap, out);
    }
}